// Round 6
// baseline (441.938 us; speedup 1.0000x reference)
//
#include <hip/hip_runtime.h>

#define NNODES 50000
#define NEDGES 1600000
#define NBUCK 196      // ceil(50000/256) buckets of 256 dst nodes
#define BIN_CH 4096    // edges per block in k_bin
#define CNT_CH 4096    // edges per block in k_b0

__device__ __forceinline__ float leaky02(float x) { return x > 0.f ? x : 0.2f * x; }

// inclusive Hillis-Steele scan of 256 ints (one per thread) via scratch sh[256]
__device__ __forceinline__ int block_incl_scan(int v, int* sh) {
  int t = threadIdx.x;
  sh[t] = v;
  __syncthreads();
  for (int d = 1; d < 256; d <<= 1) {
    int u = (t >= d) ? sh[t - d] : 0;
    __syncthreads();
    sh[t] += u;
    __syncthreads();
  }
  return sh[t];
}

// ---------------- CSR build: binned counting sort ----------------
__global__ __launch_bounds__(256) void k_b0(const int* __restrict__ dst,
                                            int* __restrict__ gcnt, int E) {
  __shared__ int hist[256];
  int t = threadIdx.x;
  hist[t] = 0;
  __syncthreads();
  int base0 = blockIdx.x * CNT_CH;
#pragma unroll
  for (int r = 0; r < CNT_CH / 256; ++r) {
    int idx = base0 + r * 256 + t;
    if (idx < E) atomicAdd(&hist[dst[idx] >> 8], 1);
  }
  __syncthreads();
  if (t < NBUCK && hist[t]) atomicAdd(&gcnt[t], hist[t]);
}

__global__ __launch_bounds__(256) void k_b1(const int* __restrict__ gcnt,
                                            int* __restrict__ base,
                                            int* __restrict__ cursor) {
  __shared__ int sh[256];
  int t = threadIdx.x;
  int v = (t < NBUCK) ? gcnt[t] : 0;
  int incl = block_incl_scan(v, sh);
  if (t < NBUCK) {
    base[t] = incl - v;
    cursor[t] = incl - v;
  }
  if (t == 255) base[NBUCK] = NEDGES;
}

// k_bin: pack (dst<<16)|src, per-bucket reservation, direct global scatter.
__global__ __launch_bounds__(256) void k_bin(const int* __restrict__ src,
                                             const int* __restrict__ dst,
                                             int* __restrict__ cursor,
                                             unsigned* __restrict__ binned, int E) {
  __shared__ int hist[256];
  __shared__ int cur[256];
  int t = threadIdx.x;
  int base0 = blockIdx.x * BIN_CH;
  unsigned pk[BIN_CH / 256];
  hist[t] = 0;
  __syncthreads();
#pragma unroll
  for (int r = 0; r < BIN_CH / 256; ++r) {
    int idx = base0 + r * 256 + t;
    if (idx < E) {
      unsigned p = ((unsigned)dst[idx] << 16) | (unsigned)src[idx];
      pk[r] = p;
      atomicAdd(&hist[p >> 24], 1);
    }
  }
  __syncthreads();
  if (t < NBUCK && hist[t]) cur[t] = atomicAdd(&cursor[t], hist[t]);
  __syncthreads();
#pragma unroll
  for (int r = 0; r < BIN_CH / 256; ++r) {
    int idx = base0 + r * 256 + t;
    if (idx < E) {
      unsigned p = pk[r];
      int pos = atomicAdd(&cur[p >> 24], 1);
      binned[pos] = p;
    }
  }
}

__global__ __launch_bounds__(256) void k_sort(const unsigned* __restrict__ binned,
                                              const int* __restrict__ base,
                                              int* __restrict__ deg,
                                              int* __restrict__ offs,
                                              int* __restrict__ csr) {
  __shared__ int hist[256];
  __shared__ int scanbuf[256];
  __shared__ int cur[256];
  int t = threadIdx.x;
  int b = blockIdx.x;
  int lo = base[b], hi = base[b + 1];
  int node0 = b << 8;
  hist[t] = 0;
  __syncthreads();
  for (int i = lo + t; i < hi; i += 256)
    atomicAdd(&hist[(binned[i] >> 16) & 255], 1);
  __syncthreads();
  int h = hist[t];
  int incl = block_incl_scan(h, scanbuf);
  int excl = incl - h;
  int node = node0 + t;
  if (node < NNODES) {
    deg[node] = h;
    offs[node] = lo + excl;
  }
  cur[t] = lo + excl;
  __syncthreads();
  for (int i = lo + t; i < hi; i += 256) {
    unsigned p = binned[i];
    int pos = atomicAdd(&cur[(p >> 16) & 255], 1);
    csr[pos] = (int)(p & 0xFFFFu);
  }
}

// ---------------- Tiled GEMM v4: 64 rows x NC cols per block (2x grid) ----------
// KC=64 (fewest barriers); unpadded row-major As (b128 broadcast = conflict-free,
// verified SQ_LDS_BANK_CONFLICT=0). BN scale/shift computed in-block. Thread tile
// 4 rows (strided 16) x TN cols.
template <int K, int KC, int NC, int TN, int SPLIT, bool BN, bool STATS>
__global__ __launch_bounds__(256) void k_gemm(
    const float* __restrict__ A, const float* __restrict__ bn_sum,
    const float* __restrict__ bn_sq, const float* __restrict__ bn_gamma,
    const float* __restrict__ bn_beta, float invM,
    const float* __restrict__ B0, const float* __restrict__ B1,
    const float* __restrict__ bias0,
    float* __restrict__ out0, float* __restrict__ out1,
    float* __restrict__ gsum, float* __restrict__ gsq, int M) {
  __shared__ float As[64 * KC];
  __shared__ float Bs[KC * NC];
  __shared__ float scS[BN ? K : 4];
  __shared__ float shS[BN ? K : 4];
  const int tid = threadIdx.x;
  const int row0 = blockIdx.x * 64;
  const int cg = tid & 15;          // 16 col groups of TN
  const int rowg = (tid >> 4) & 15; // 16 row groups; rows rowg + 16*r, r<4

  if constexpr (BN) {
    if (tid < K) {
      float mean = bn_sum[tid] * invM;
      float var = bn_sq[tid] * invM - mean * mean;  // biased, matches jnp.var
      float rs = rsqrtf(var + 1e-5f);
      float sc = rs * bn_gamma[tid];
      scS[tid] = sc;
      shS[tid] = bn_beta[tid] - mean * sc;
    }
    __syncthreads();
  }

  float acc[4][TN];
#pragma unroll
  for (int r = 0; r < 4; ++r)
#pragma unroll
    for (int j = 0; j < TN; ++j) acc[r][j] = 0.f;

  constexpr int KB = KC / 4;  // float4 slots per A row
  for (int k0 = 0; k0 < K; k0 += KC) {
    // ---- stage A (row-major, float4, BN applied on the fly) ----
#pragma unroll
    for (int it = 0; it < (64 * KB) / 256; ++it) {
      int idx = tid + it * 256;
      int row = idx / KB;
      int kb = idx % KB;
      float4 v = make_float4(0.f, 0.f, 0.f, 0.f);
      int grow = row0 + row;
      if (grow < M) {
        v = *reinterpret_cast<const float4*>(&A[(size_t)grow * K + k0 + kb * 4]);
        if constexpr (BN) {
          int kb4 = k0 + kb * 4;
          float4 sc = *reinterpret_cast<const float4*>(&scS[kb4]);
          float4 sf = *reinterpret_cast<const float4*>(&shS[kb4]);
          v.x = fmaxf(v.x * sc.x + sf.x, 0.f);
          v.y = fmaxf(v.y * sc.y + sf.y, 0.f);
          v.z = fmaxf(v.z * sc.z + sf.z, 0.f);
          v.w = fmaxf(v.w * sc.w + sf.w, 0.f);
        }
      }
      *reinterpret_cast<float4*>(&As[row * KC + kb * 4]) = v;
    }
    // ---- stage B (float4) ----
    {
      constexpr int KB0 = SPLIT / 4;
#pragma unroll
      for (int it = 0; it < (KC * KB0) / 256; ++it) {
        int idx = tid + it * 256;
        int kk = idx / KB0;
        int cb = idx % KB0;
        float4 v = *reinterpret_cast<const float4*>(&B0[(size_t)(k0 + kk) * SPLIT + cb * 4]);
        *reinterpret_cast<float4*>(&Bs[kk * NC + cb * 4]) = v;
      }
    }
    if constexpr (NC > SPLIT) {
      constexpr int W1 = NC - SPLIT;
      constexpr int KB1 = W1 / 4;
#pragma unroll
      for (int it = 0; it < (KC * KB1) / 256; ++it) {
        int idx = tid + it * 256;
        int kk = idx / KB1;
        int cb = idx % KB1;
        float4 v = *reinterpret_cast<const float4*>(&B1[(size_t)(k0 + kk) * W1 + cb * 4]);
        *reinterpret_cast<float4*>(&Bs[kk * NC + SPLIT + cb * 4]) = v;
      }
    }
    __syncthreads();
    // ---- compute: 4 k's per iteration ----
    for (int kk = 0; kk < KC; kk += 4) {
      float4 a[4];
#pragma unroll
      for (int r = 0; r < 4; ++r)
        a[r] = *reinterpret_cast<const float4*>(&As[(rowg + 16 * r) * KC + kk]);
      float b[4][TN];
#pragma unroll
      for (int i = 0; i < 4; ++i)
#pragma unroll
        for (int j = 0; j < TN; ++j) b[i][j] = Bs[(kk + i) * NC + cg * TN + j];
#pragma unroll
      for (int r = 0; r < 4; ++r)
#pragma unroll
        for (int j = 0; j < TN; ++j) {
          acc[r][j] += a[r].x * b[0][j];
          acc[r][j] += a[r].y * b[1][j];
          acc[r][j] += a[r].z * b[2][j];
          acc[r][j] += a[r].w * b[3][j];
        }
    }
    __syncthreads();
  }
  // ---- epilogue ----
  float bias_r[TN];
#pragma unroll
  for (int j = 0; j < TN; ++j) {
    int c = cg * TN + j;
    bias_r[j] = (c < SPLIT) ? bias0[c] : 0.f;
  }
  float cs[TN], cq[TN];
#pragma unroll
  for (int j = 0; j < TN; ++j) { cs[j] = 0.f; cq[j] = 0.f; }
#pragma unroll
  for (int r = 0; r < 4; ++r) {
    int grow = row0 + rowg + 16 * r;
    if (grow < M) {
#pragma unroll
      for (int j = 0; j < TN; ++j) {
        int c = cg * TN + j;
        if (c < SPLIT) {
          float v = acc[r][j] + bias_r[j];
          out0[(size_t)grow * SPLIT + c] = v;
          if (STATS) { cs[j] += v; cq[j] += v * v; }
        } else {
          out1[(size_t)grow * (NC - SPLIT) + (c - SPLIT)] = acc[r][j];
        }
      }
    }
  }
  if constexpr (STATS) {
#pragma unroll
    for (int j = 0; j < TN; ++j) {
      cs[j] += __shfl_xor(cs[j], 16);
      cs[j] += __shfl_xor(cs[j], 32);
      cq[j] += __shfl_xor(cq[j], 16);
      cq[j] += __shfl_xor(cq[j], 32);
    }
    float* red = Bs;  // reuse Bs: 4 waves x 2 x SPLIT floats
    int wave = tid >> 6;
    int lane = tid & 63;
    if (lane < 16) {
#pragma unroll
      for (int j = 0; j < TN; ++j) {
        int c = cg * TN + j;
        if (c < SPLIT) {
          red[wave * 2 * SPLIT + c] = cs[j];
          red[wave * 2 * SPLIT + SPLIT + c] = cq[j];
        }
      }
    }
    __syncthreads();
    if (tid < SPLIT) {
      float s = red[tid] + red[2 * SPLIT + tid] + red[4 * SPLIT + tid] + red[6 * SPLIT + tid];
      atomicAdd(&gsum[tid], s);
    } else if (tid < 2 * SPLIT) {
      int c = tid - SPLIT;
      float q = red[SPLIT + c] + red[3 * SPLIT + c] + red[5 * SPLIT + c] + red[7 * SPLIT + c];
      atomicAdd(&gsq[c], q);
    }
  }
}

// ---------------- per-row attention scalars s = g.as, d = g.ad ----------------
__global__ __launch_bounds__(256) void k_sdot(const float* __restrict__ g,
                                              const float* __restrict__ as_,
                                              const float* __restrict__ ad_,
                                              float* __restrict__ sv,
                                              float* __restrict__ dv, int N) {
  int lane = threadIdx.x & 31;
  int row = blockIdx.x * 8 + (threadIdx.x >> 5);
  if (row >= N) return;
  float v = g[(size_t)row * 32 + lane];
  float a = v * as_[lane];
  float b = v * ad_[lane];
#pragma unroll
  for (int w = 16; w >= 1; w >>= 1) {
    a += __shfl_xor(a, w);
    b += __shfl_xor(b, w);
  }
  if (lane == 0) {
    sv[row] = a;
    dv[row] = b;
  }
}

// ---------------- GAT aggregation: half-wave per node, 8-way unrolled gathers ----
__global__ __launch_bounds__(256) void k_gat_agg(
    const float* __restrict__ h, const float* __restrict__ sv,
    const float* __restrict__ dv, const int* __restrict__ offs,
    const int* __restrict__ deg, const int* __restrict__ csr,
    const float* __restrict__ bias, float* __restrict__ out, int N) {
  int lane = threadIdx.x & 31;
  int node = blockIdx.x * 8 + (threadIdx.x >> 5);
  if (node >= N) return;
  int start = offs[node];
  int cnt = deg[node];
  float di = dv[node];
  float ex0 = __expf(leaky02(sv[node] + di));  // self-loop (softmax shift-free)
  float den = ex0;
  float acc = ex0 * h[(size_t)node * 32 + lane];
  int k = 0;
  for (; k + 8 <= cnt; k += 8) {
    int j0 = csr[start + k + 0], j1 = csr[start + k + 1];
    int j2 = csr[start + k + 2], j3 = csr[start + k + 3];
    int j4 = csr[start + k + 4], j5 = csr[start + k + 5];
    int j6 = csr[start + k + 6], j7 = csr[start + k + 7];
    float s0 = sv[j0], s1 = sv[j1], s2 = sv[j2], s3 = sv[j3];
    float s4 = sv[j4], s5 = sv[j5], s6 = sv[j6], s7 = sv[j7];
    float h0 = h[(size_t)j0 * 32 + lane], h1 = h[(size_t)j1 * 32 + lane];
    float h2 = h[(size_t)j2 * 32 + lane], h3 = h[(size_t)j3 * 32 + lane];
    float h4 = h[(size_t)j4 * 32 + lane], h5 = h[(size_t)j5 * 32 + lane];
    float h6 = h[(size_t)j6 * 32 + lane], h7 = h[(size_t)j7 * 32 + lane];
    float e0 = __expf(leaky02(s0 + di)), e1 = __expf(leaky02(s1 + di));
    float e2 = __expf(leaky02(s2 + di)), e3 = __expf(leaky02(s3 + di));
    float e4 = __expf(leaky02(s4 + di)), e5 = __expf(leaky02(s5 + di));
    float e6 = __expf(leaky02(s6 + di)), e7 = __expf(leaky02(s7 + di));
    den += ((e0 + e1) + (e2 + e3)) + ((e4 + e5) + (e6 + e7));
    acc += e0 * h0 + e1 * h1 + e2 * h2 + e3 * h3;
    acc += e4 * h4 + e5 * h5 + e6 * h6 + e7 * h7;
  }
  for (; k < cnt; ++k) {
    int j = csr[start + k];
    float ex = __expf(leaky02(sv[j] + di));
    den += ex;
    acc += ex * h[(size_t)j * 32 + lane];
  }
  out[(size_t)node * 32 + lane] = fmaxf(acc / den + bias[lane], 0.f);
}

// ---------------- small 32x32 GEMM (h1 @ W_g2) fused with s2/d2 ----------------
__global__ __launch_bounds__(256) void k_small_gemm_sd(
    const float* __restrict__ hin, const float* __restrict__ W,
    const float* __restrict__ as_, const float* __restrict__ ad_,
    float* __restrict__ gout, float* __restrict__ sv, float* __restrict__ dv,
    int N) {
  __shared__ float Ws[32][32];
  {
    int t = threadIdx.x;
#pragma unroll
    for (int r = 0; r < 4; ++r) {
      int idx = t + r * 256;
      Ws[idx >> 5][idx & 31] = W[idx];
    }
  }
  __syncthreads();
  int lane = threadIdx.x & 31;
  int row = blockIdx.x * 8 + (threadIdx.x >> 5);
  if (row >= N) return;
  float hv = hin[(size_t)row * 32 + lane];
  float acc = 0.f;
#pragma unroll
  for (int k = 0; k < 32; ++k) acc += __shfl(hv, k, 32) * Ws[k][lane];
  gout[(size_t)row * 32 + lane] = acc;
  float a = acc * as_[lane];
  float b = acc * ad_[lane];
#pragma unroll
  for (int w = 16; w >= 1; w >>= 1) {
    a += __shfl_xor(a, w);
    b += __shfl_xor(b, w);
  }
  if (lane == 0) {
    sv[row] = a;
    dv[row] = b;
  }
}

// ---------------- k_final2: 64 rows x 256 cols per block, fused BN3 finalize ----
__global__ __launch_bounds__(256) void k_final2(
    const float* __restrict__ mlp3, const float* __restrict__ sum3,
    const float* __restrict__ sq3, const float* __restrict__ g3,
    const float* __restrict__ be3, float invM, const float* __restrict__ h2,
    const float* __restrict__ Wgf, const float* __restrict__ bgf,
    const float* __restrict__ Wf, const float* __restrict__ bf,
    float* __restrict__ out, int N) {
  __shared__ float WfS[32 * 256];    // 32 KB
  __shared__ float Bl[64][36];       // h2 tile, then blend tile
  __shared__ float WgfS[32][33];
  __shared__ float colS[3][32];      // sc3, sh3, bgf
  const int t = threadIdx.x;
  const int row0 = blockIdx.x * 64;

  {
    const float4* src = reinterpret_cast<const float4*>(Wf);
    float4* dst = reinterpret_cast<float4*>(WfS);
#pragma unroll
    for (int r = 0; r < 8; ++r) dst[t + r * 256] = src[t + r * 256];
  }
#pragma unroll
  for (int r = 0; r < 4; ++r) {
    int idx = t + r * 256;
    WgfS[idx >> 5][idx & 31] = Wgf[idx];
  }
  if (t < 32) {
    float mean = sum3[t] * invM;
    float var = sq3[t] * invM - mean * mean;
    float rs = rsqrtf(var + 1e-5f);
    float sc = rs * g3[t];
    colS[0][t] = sc;
    colS[1][t] = be3[t] - mean * sc;
    colS[2][t] = bgf[t];
  }
#pragma unroll
  for (int r = 0; r < 2; ++r) {
    int idx = t + r * 256;   // 0..511
    int row = idx >> 3;
    int k4 = idx & 7;
    int grow = row0 + row;
    float4 v = make_float4(0.f, 0.f, 0.f, 0.f);
    if (grow < N) v = *reinterpret_cast<const float4*>(&h2[(size_t)grow * 32 + k4 * 4]);
    *reinterpret_cast<float4*>(&Bl[row][k4 * 4]) = v;
  }
  __syncthreads();

  // ---- phase 1: blend ----
  const int col = t & 31;
  const int rb = t >> 5;
  float w[32];
#pragma unroll
  for (int k = 0; k < 32; ++k) w[k] = WgfS[k][col];
  float bl[8];
#pragma unroll
  for (int r = 0; r < 8; ++r) {
    int row = rb + 8 * r;
    float a = colS[2][col];
#pragma unroll
    for (int k4 = 0; k4 < 8; ++k4) {
      float4 hv = *reinterpret_cast<const float4*>(&Bl[row][k4 * 4]);
      a += hv.x * w[k4 * 4 + 0] + hv.y * w[k4 * 4 + 1] +
           hv.z * w[k4 * 4 + 2] + hv.w * w[k4 * 4 + 3];
    }
    int grow = row0 + row;
    float pre = (grow < N) ? mlp3[(size_t)grow * 32 + col] : 0.f;
    float rv = fmaxf(pre * colS[0][col] + colS[1][col], 0.f);
    bl[r] = 0.5f * rv + 0.5f * a;
  }
  __syncthreads();
#pragma unroll
  for (int r = 0; r < 8; ++r) Bl[rb + 8 * r][col] = bl[r];
  __syncthreads();

  // ---- phase 2: out = relu(blend @ Wf + bf) ----
  const int cg = t & 31;
  const int rowg = t >> 5;
  const float4* Wf4 = reinterpret_cast<const float4*>(WfS);
  float4 acc0[8], acc1[8];
#pragma unroll
  for (int r = 0; r < 8; ++r) {
    acc0[r] = make_float4(0.f, 0.f, 0.f, 0.f);
    acc1[r] = make_float4(0.f, 0.f, 0.f, 0.f);
  }
  for (int k = 0; k < 32; k += 4) {
    float4 a[8];
#pragma unroll
    for (int r = 0; r < 8; ++r)
      a[r] = *reinterpret_cast<const float4*>(&Bl[rowg + 8 * r][k]);
    float4 b0[4], b1[4];
#pragma unroll
    for (int i = 0; i < 4; ++i) {
      b0[i] = Wf4[(k + i) * 64 + cg];
      b1[i] = Wf4[(k + i) * 64 + cg + 32];
    }
#pragma unroll
    for (int r = 0; r < 8; ++r) {
      float av[4] = {a[r].x, a[r].y, a[r].z, a[r].w};
#pragma unroll
      for (int i = 0; i < 4; ++i) {
        acc0[r].x += av[i] * b0[i].x;
        acc0[r].y += av[i] * b0[i].y;
        acc0[r].z += av[i] * b0[i].z;
        acc0[r].w += av[i] * b0[i].w;
        acc1[r].x += av[i] * b1[i].x;
        acc1[r].y += av[i] * b1[i].y;
        acc1[r].z += av[i] * b1[i].z;
        acc1[r].w += av[i] * b1[i].w;
      }
    }
  }
  float4 bfA = reinterpret_cast<const float4*>(bf)[cg];
  float4 bfB = reinterpret_cast<const float4*>(bf)[cg + 32];
  float4* out4 = reinterpret_cast<float4*>(out);
#pragma unroll
  for (int r = 0; r < 8; ++r) {
    int grow = row0 + rowg + 8 * r;
    if (grow < N) {
      float4 o0 = acc0[r], o1 = acc1[r];
      o0.x = fmaxf(o0.x + bfA.x, 0.f); o0.y = fmaxf(o0.y + bfA.y, 0.f);
      o0.z = fmaxf(o0.z + bfA.z, 0.f); o0.w = fmaxf(o0.w + bfA.w, 0.f);
      o1.x = fmaxf(o1.x + bfB.x, 0.f); o1.y = fmaxf(o1.y + bfB.y, 0.f);
      o1.z = fmaxf(o1.z + bfB.z, 0.f); o1.w = fmaxf(o1.w + bfB.w, 0.f);
      out4[(size_t)grow * 64 + cg] = o0;
      out4[(size_t)grow * 64 + cg + 32] = o1;
    }
  }
}

extern "C" void kernel_launch(void* const* d_in, const int* in_sizes, int n_in,
                              void* d_out, int out_size, void* d_ws, size_t ws_size,
                              hipStream_t stream) {
  const float* x = (const float*)d_in[0];
  const int* edge = (const int*)d_in[1];
  const float* W_g1 = (const float*)d_in[2];
  const float* as_g1 = (const float*)d_in[3];
  const float* ad_g1 = (const float*)d_in[4];
  const float* b_g1 = (const float*)d_in[5];
  const float* W_g2 = (const float*)d_in[6];
  const float* as_g2 = (const float*)d_in[7];
  const float* ad_g2 = (const float*)d_in[8];
  const float* b_g2 = (const float*)d_in[9];
  const float* W_gf = (const float*)d_in[10];
  const float* b_gf = (const float*)d_in[11];
  const float* W_m1 = (const float*)d_in[12];
  const float* b_m1 = (const float*)d_in[13];
  const float* g_m1 = (const float*)d_in[14];
  const float* be_m1 = (const float*)d_in[15];
  const float* W_m2 = (const float*)d_in[16];
  const float* b_m2 = (const float*)d_in[17];
  const float* g_m2 = (const float*)d_in[18];
  const float* be_m2 = (const float*)d_in[19];
  const float* W_m3 = (const float*)d_in[20];
  const float* b_m3 = (const float*)d_in[21];
  const float* g_m3 = (const float*)d_in[22];
  const float* be_m3 = (const float*)d_in[23];
  const float* W_f = (const float*)d_in[24];
  const float* b_f = (const float*)d_in[25];
  float* out = (float*)d_out;

  const int N = NNODES, E = NEDGES;
  const float invM = 1.f / N;
  const int* esrc = edge;
  const int* edst = edge + E;

  // ---- workspace layout ----
  float* ws = (float*)d_ws;
  float* g1 = ws;                              // N*32
  float* mlp1 = g1 + (size_t)N * 32;           // N*64
  float* mlp2 = mlp1 + (size_t)N * 64;         // N*64 (first 6.4MB doubles as binned[] early)
  float* mlp3 = mlp2 + (size_t)N * 64;         // N*32
  float* h1 = mlp3 + (size_t)N * 32;           // N*32
  float* g2 = h1 + (size_t)N * 32;             // N*32
  float* h2 = g2 + (size_t)N * 32;             // N*32
  float* s1 = h2 + (size_t)N * 32;             // N
  float* d1 = s1 + N;
  float* s2 = d1 + N;
  float* d2 = s2 + N;
  float* stats = d2 + N;                        // 384 floats (zeroed)
  float* sum1 = stats, *sq1 = stats + 64;
  float* sum2 = stats + 128, *sq2 = stats + 192;
  float* sum3 = stats + 256, *sq3 = stats + 288;
  int* ip = (int*)(stats + 384);
  int* gcnt = ip;              // 256 (zeroed)
  int* base = gcnt + 256;      // 256 (197 used)
  int* cursor = base + 256;    // 256
  int* deg = cursor + 256;     // N
  int* offs = deg + N;         // N
  int* csr = offs + N;         // E
  unsigned* binned = (unsigned*)mlp2;  // E (dead before gemm2 writes mlp2)

  hipMemsetAsync(gcnt, 0, 256 * sizeof(int), stream);
  hipMemsetAsync(stats, 0, 384 * sizeof(float), stream);

  // ---- CSR build via binned counting sort ----
  k_b0<<<(E + CNT_CH - 1) / CNT_CH, 256, 0, stream>>>(edst, gcnt, E);
  k_b1<<<1, 256, 0, stream>>>(gcnt, base, cursor);
  k_bin<<<(E + BIN_CH - 1) / BIN_CH, 256, 0, stream>>>(esrc, edst, cursor, binned, E);
  k_sort<<<NBUCK, 256, 0, stream>>>(binned, base, deg, offs, csr);

  const int GB = (N + 63) / 64;  // 782 blocks for the 64-row GEMMs

  // ---- fused first layer: x @ [W_m1 | W_g1] -> mlp1 (+b_m1, +stats), g1 ----
  k_gemm<256, 64, 96, 6, 64, false, true><<<GB, 256, 0, stream>>>(
      x, nullptr, nullptr, nullptr, nullptr, invM, W_m1, W_g1, b_m1,
      mlp1, g1, sum1, sq1, N);
  k_sdot<<<(N + 7) / 8, 256, 0, stream>>>(g1, as_g1, ad_g1, s1, d1, N);
  k_gat_agg<<<(N + 7) / 8, 256, 0, stream>>>(g1, s1, d1, offs, deg, csr, b_g1, h1, N);

  // ---- MLP layer 2: BN1+ReLU(mlp1) @ W_m2 + b_m2 (+stats) ----
  k_gemm<64, 64, 64, 4, 64, true, true><<<GB, 256, 0, stream>>>(
      mlp1, sum1, sq1, g_m1, be_m1, invM, W_m2, nullptr, b_m2,
      mlp2, nullptr, sum2, sq2, N);

  // ---- GAT layer 2 ----
  k_small_gemm_sd<<<(N + 7) / 8, 256, 0, stream>>>(h1, W_g2, as_g2, ad_g2, g2, s2, d2, N);
  k_gat_agg<<<(N + 7) / 8, 256, 0, stream>>>(g2, s2, d2, offs, deg, csr, b_g2, h2, N);

  // ---- MLP layer 3: BN2+ReLU(mlp2) @ W_m3 + b_m3 (+stats) ----
  k_gemm<64, 64, 32, 2, 32, true, true><<<GB, 256, 0, stream>>>(
      mlp2, sum2, sq2, g_m2, be_m2, invM, W_m3, nullptr, b_m3,
      mlp3, nullptr, sum3, sq3, N);

  // ---- final fused: BN3 + blend + @W_f + b_f + ReLU ----
  k_final2<<<(N + 63) / 64, 256, 0, stream>>>(mlp3, sum3, sq3, g_m3, be_m3, invM,
                                              h2, W_gf, b_gf, W_f, b_f, out, N);
}

// Round 7
// 417.363 us; speedup vs baseline: 1.0589x; 1.0589x over previous
//
#include <hip/hip_runtime.h>

#define NNODES 50000
#define NEDGES 1600000
#define NBUCK 196      // ceil(50000/256) buckets of 256 dst nodes
#define BIN_CH 4096    // edges per block in k_bin
#define CNT_CH 4096    // edges per block in k_b0

__device__ __forceinline__ float leaky02(float x) { return x > 0.f ? x : 0.2f * x; }

// inclusive Hillis-Steele scan of 256 ints (one per thread) via scratch sh[256]
__device__ __forceinline__ int block_incl_scan(int v, int* sh) {
  int t = threadIdx.x;
  sh[t] = v;
  __syncthreads();
  for (int d = 1; d < 256; d <<= 1) {
    int u = (t >= d) ? sh[t - d] : 0;
    __syncthreads();
    sh[t] += u;
    __syncthreads();
  }
  return sh[t];
}

// ---------------- CSR build: binned counting sort ----------------
__global__ __launch_bounds__(256) void k_b0(const int* __restrict__ dst,
                                            int* __restrict__ gcnt, int E) {
  __shared__ int hist[256];
  int t = threadIdx.x;
  hist[t] = 0;
  __syncthreads();
  int base0 = blockIdx.x * CNT_CH;
#pragma unroll
  for (int r = 0; r < CNT_CH / 256; ++r) {
    int idx = base0 + r * 256 + t;
    if (idx < E) atomicAdd(&hist[dst[idx] >> 8], 1);
  }
  __syncthreads();
  if (t < NBUCK && hist[t]) atomicAdd(&gcnt[t], hist[t]);
}

__global__ __launch_bounds__(256) void k_b1(const int* __restrict__ gcnt,
                                            int* __restrict__ base,
                                            int* __restrict__ cursor) {
  __shared__ int sh[256];
  int t = threadIdx.x;
  int v = (t < NBUCK) ? gcnt[t] : 0;
  int incl = block_incl_scan(v, sh);
  if (t < NBUCK) {
    base[t] = incl - v;
    cursor[t] = incl - v;
  }
  if (t == 255) base[NBUCK] = NEDGES;
}

// k_bin: pack (dst<<16)|src, per-bucket reservation, direct global scatter.
__global__ __launch_bounds__(256) void k_bin(const int* __restrict__ src,
                                             const int* __restrict__ dst,
                                             int* __restrict__ cursor,
                                             unsigned* __restrict__ binned, int E) {
  __shared__ int hist[256];
  __shared__ int cur[256];
  int t = threadIdx.x;
  int base0 = blockIdx.x * BIN_CH;
  unsigned pk[BIN_CH / 256];
  hist[t] = 0;
  __syncthreads();
#pragma unroll
  for (int r = 0; r < BIN_CH / 256; ++r) {
    int idx = base0 + r * 256 + t;
    if (idx < E) {
      unsigned p = ((unsigned)dst[idx] << 16) | (unsigned)src[idx];
      pk[r] = p;
      atomicAdd(&hist[p >> 24], 1);
    }
  }
  __syncthreads();
  if (t < NBUCK && hist[t]) cur[t] = atomicAdd(&cursor[t], hist[t]);
  __syncthreads();
#pragma unroll
  for (int r = 0; r < BIN_CH / 256; ++r) {
    int idx = base0 + r * 256 + t;
    if (idx < E) {
      unsigned p = pk[r];
      int pos = atomicAdd(&cur[p >> 24], 1);
      binned[pos] = p;
    }
  }
}

__global__ __launch_bounds__(256) void k_sort(const unsigned* __restrict__ binned,
                                              const int* __restrict__ base,
                                              int* __restrict__ deg,
                                              int* __restrict__ offs,
                                              int* __restrict__ csr) {
  __shared__ int hist[256];
  __shared__ int scanbuf[256];
  __shared__ int cur[256];
  int t = threadIdx.x;
  int b = blockIdx.x;
  int lo = base[b], hi = base[b + 1];
  int node0 = b << 8;
  hist[t] = 0;
  __syncthreads();
  for (int i = lo + t; i < hi; i += 256)
    atomicAdd(&hist[(binned[i] >> 16) & 255], 1);
  __syncthreads();
  int h = hist[t];
  int incl = block_incl_scan(h, scanbuf);
  int excl = incl - h;
  int node = node0 + t;
  if (node < NNODES) {
    deg[node] = h;
    offs[node] = lo + excl;
  }
  cur[t] = lo + excl;
  __syncthreads();
  for (int i = lo + t; i < hi; i += 256) {
    unsigned p = binned[i];
    int pos = atomicAdd(&cur[(p >> 16) & 255], 1);
    csr[pos] = (int)(p & 0xFFFFu);
  }
}

// ---------------- Tiled GEMM v5: ROWS x NC per block, XOR-swizzled As ----------
// KC=64. As row-major [ROWS][64] with float4-slot swizzle (slot ^= row&3):
// conflict-free reads without padding (keeps gemm1 at exactly 40 KB = 4 blocks/CU).
// BN scale/shift computed in-block from global sum/sq. Thread tile (ROWS/16) x TN.
template <int K, int NC, int TN, int SPLIT, bool BN, bool STATS, int ROWS>
__global__ __launch_bounds__(256) void k_gemm(
    const float* __restrict__ A, const float* __restrict__ bn_sum,
    const float* __restrict__ bn_sq, const float* __restrict__ bn_gamma,
    const float* __restrict__ bn_beta, float invM,
    const float* __restrict__ B0, const float* __restrict__ B1,
    const float* __restrict__ bias0,
    float* __restrict__ out0, float* __restrict__ out1,
    float* __restrict__ gsum, float* __restrict__ gsq, int M) {
  constexpr int KC = 64;
  constexpr int RPT = ROWS / 16;  // rows per thread
  __shared__ float As[ROWS * KC];
  __shared__ float Bs[KC * NC];
  __shared__ float scS[BN ? K : 4];   // eliminated by compiler when !BN
  __shared__ float shS[BN ? K : 4];
  const int tid = threadIdx.x;
  const int row0 = blockIdx.x * ROWS;
  const int cg = tid & 15;          // 16 col groups of TN
  const int rowg = (tid >> 4) & 15; // 16 row groups; rows rowg + 16*r
  const int swz = (rowg & 3) << 2;  // per-thread read swizzle (row&3 == rowg&3)

  if constexpr (BN) {
    if (tid < K) {
      float mean = bn_sum[tid] * invM;
      float var = bn_sq[tid] * invM - mean * mean;  // biased, matches jnp.var
      float rs = rsqrtf(var + 1e-5f);
      float sc = rs * bn_gamma[tid];
      scS[tid] = sc;
      shS[tid] = bn_beta[tid] - mean * sc;
    }
    __syncthreads();
  }

  float acc[RPT][TN];
#pragma unroll
  for (int r = 0; r < RPT; ++r)
#pragma unroll
    for (int j = 0; j < TN; ++j) acc[r][j] = 0.f;

  constexpr int KB = KC / 4;  // 16 float4 slots per A row
  for (int k0 = 0; k0 < K; k0 += KC) {
    // ---- stage A (float4, swizzled slot, BN applied on the fly) ----
#pragma unroll
    for (int it = 0; it < (ROWS * KB) / 256; ++it) {
      int idx = tid + it * 256;
      int row = idx / KB;
      int kb = idx % KB;
      float4 v = make_float4(0.f, 0.f, 0.f, 0.f);
      int grow = row0 + row;
      if (grow < M) {
        v = *reinterpret_cast<const float4*>(&A[(size_t)grow * K + k0 + kb * 4]);
        if constexpr (BN) {
          int kb4 = k0 + kb * 4;
          float4 sc = *reinterpret_cast<const float4*>(&scS[kb4]);
          float4 sf = *reinterpret_cast<const float4*>(&shS[kb4]);
          v.x = fmaxf(v.x * sc.x + sf.x, 0.f);
          v.y = fmaxf(v.y * sc.y + sf.y, 0.f);
          v.z = fmaxf(v.z * sc.z + sf.z, 0.f);
          v.w = fmaxf(v.w * sc.w + sf.w, 0.f);
        }
      }
      *reinterpret_cast<float4*>(&As[row * KC + ((kb ^ (row & 3)) * 4)]) = v;
    }
    // ---- stage B (float4) ----
    {
      constexpr int KB0 = SPLIT / 4;
#pragma unroll
      for (int it = 0; it < (KC * KB0) / 256; ++it) {
        int idx = tid + it * 256;
        int kk = idx / KB0;
        int cb = idx % KB0;
        float4 v = *reinterpret_cast<const float4*>(&B0[(size_t)(k0 + kk) * SPLIT + cb * 4]);
        *reinterpret_cast<float4*>(&Bs[kk * NC + cb * 4]) = v;
      }
    }
    if constexpr (NC > SPLIT) {
      constexpr int W1 = NC - SPLIT;
      constexpr int KB1 = W1 / 4;
#pragma unroll
      for (int it = 0; it < (KC * KB1) / 256; ++it) {
        int idx = tid + it * 256;
        int kk = idx / KB1;
        int cb = idx % KB1;
        float4 v = *reinterpret_cast<const float4*>(&B1[(size_t)(k0 + kk) * W1 + cb * 4]);
        *reinterpret_cast<float4*>(&Bs[kk * NC + SPLIT + cb * 4]) = v;
      }
    }
    __syncthreads();
    // ---- compute: 4 k's per iteration ----
    for (int kk = 0; kk < KC; kk += 4) {
      float4 a[RPT];
#pragma unroll
      for (int r = 0; r < RPT; ++r)
        a[r] = *reinterpret_cast<const float4*>(&As[(rowg + 16 * r) * KC + (kk ^ swz)]);
      float b[4][TN];
#pragma unroll
      for (int i = 0; i < 4; ++i)
#pragma unroll
        for (int j = 0; j < TN; ++j) b[i][j] = Bs[(kk + i) * NC + cg * TN + j];
#pragma unroll
      for (int r = 0; r < RPT; ++r)
#pragma unroll
        for (int j = 0; j < TN; ++j) {
          acc[r][j] += a[r].x * b[0][j];
          acc[r][j] += a[r].y * b[1][j];
          acc[r][j] += a[r].z * b[2][j];
          acc[r][j] += a[r].w * b[3][j];
        }
    }
    __syncthreads();
  }
  // ---- epilogue ----
  float bias_r[TN];
#pragma unroll
  for (int j = 0; j < TN; ++j) {
    int c = cg * TN + j;
    bias_r[j] = (c < SPLIT) ? bias0[c] : 0.f;
  }
  float cs[TN], cq[TN];
#pragma unroll
  for (int j = 0; j < TN; ++j) { cs[j] = 0.f; cq[j] = 0.f; }
#pragma unroll
  for (int r = 0; r < RPT; ++r) {
    int grow = row0 + rowg + 16 * r;
    if (grow < M) {
#pragma unroll
      for (int j = 0; j < TN; ++j) {
        int c = cg * TN + j;
        if (c < SPLIT) {
          float v = acc[r][j] + bias_r[j];
          out0[(size_t)grow * SPLIT + c] = v;
          if (STATS) { cs[j] += v; cq[j] += v * v; }
        } else {
          out1[(size_t)grow * (NC - SPLIT) + (c - SPLIT)] = acc[r][j];
        }
      }
    }
  }
  if constexpr (STATS) {
#pragma unroll
    for (int j = 0; j < TN; ++j) {
      cs[j] += __shfl_xor(cs[j], 16);
      cs[j] += __shfl_xor(cs[j], 32);
      cq[j] += __shfl_xor(cq[j], 16);
      cq[j] += __shfl_xor(cq[j], 32);
    }
    float* red = Bs;  // reuse Bs: 4 waves x 2 x SPLIT floats
    int wave = tid >> 6;
    int lane = tid & 63;
    if (lane < 16) {
#pragma unroll
      for (int j = 0; j < TN; ++j) {
        int c = cg * TN + j;
        if (c < SPLIT) {
          red[wave * 2 * SPLIT + c] = cs[j];
          red[wave * 2 * SPLIT + SPLIT + c] = cq[j];
        }
      }
    }
    __syncthreads();
    if (tid < SPLIT) {
      float s = red[tid] + red[2 * SPLIT + tid] + red[4 * SPLIT + tid] + red[6 * SPLIT + tid];
      atomicAdd(&gsum[tid], s);
    } else if (tid < 2 * SPLIT) {
      int c = tid - SPLIT;
      float q = red[SPLIT + c] + red[3 * SPLIT + c] + red[5 * SPLIT + c] + red[7 * SPLIT + c];
      atomicAdd(&gsq[c], q);
    }
  }
}

// ---------------- per-row attention scalars s = g.as, d = g.ad ----------------
__global__ __launch_bounds__(256) void k_sdot(const float* __restrict__ g,
                                              const float* __restrict__ as_,
                                              const float* __restrict__ ad_,
                                              float* __restrict__ sv,
                                              float* __restrict__ dv, int N) {
  int lane = threadIdx.x & 31;
  int row = blockIdx.x * 8 + (threadIdx.x >> 5);
  if (row >= N) return;
  float v = g[(size_t)row * 32 + lane];
  float a = v * as_[lane];
  float b = v * ad_[lane];
#pragma unroll
  for (int w = 16; w >= 1; w >>= 1) {
    a += __shfl_xor(a, w);
    b += __shfl_xor(b, w);
  }
  if (lane == 0) {
    sv[row] = a;
    dv[row] = b;
  }
}

// ---------------- GAT aggregation: half-wave per node, 8-way unrolled gathers ----
__global__ __launch_bounds__(256) void k_gat_agg(
    const float* __restrict__ h, const float* __restrict__ sv,
    const float* __restrict__ dv, const int* __restrict__ offs,
    const int* __restrict__ deg, const int* __restrict__ csr,
    const float* __restrict__ bias, float* __restrict__ out, int N) {
  int lane = threadIdx.x & 31;
  int node = blockIdx.x * 8 + (threadIdx.x >> 5);
  if (node >= N) return;
  int start = offs[node];
  int cnt = deg[node];
  float di = dv[node];
  float ex0 = __expf(leaky02(sv[node] + di));  // self-loop (softmax shift-free)
  float den = ex0;
  float acc = ex0 * h[(size_t)node * 32 + lane];
  int k = 0;
  for (; k + 8 <= cnt; k += 8) {
    int j0 = csr[start + k + 0], j1 = csr[start + k + 1];
    int j2 = csr[start + k + 2], j3 = csr[start + k + 3];
    int j4 = csr[start + k + 4], j5 = csr[start + k + 5];
    int j6 = csr[start + k + 6], j7 = csr[start + k + 7];
    float s0 = sv[j0], s1 = sv[j1], s2 = sv[j2], s3 = sv[j3];
    float s4 = sv[j4], s5 = sv[j5], s6 = sv[j6], s7 = sv[j7];
    float h0 = h[(size_t)j0 * 32 + lane], h1 = h[(size_t)j1 * 32 + lane];
    float h2 = h[(size_t)j2 * 32 + lane], h3 = h[(size_t)j3 * 32 + lane];
    float h4 = h[(size_t)j4 * 32 + lane], h5 = h[(size_t)j5 * 32 + lane];
    float h6 = h[(size_t)j6 * 32 + lane], h7 = h[(size_t)j7 * 32 + lane];
    float e0 = __expf(leaky02(s0 + di)), e1 = __expf(leaky02(s1 + di));
    float e2 = __expf(leaky02(s2 + di)), e3 = __expf(leaky02(s3 + di));
    float e4 = __expf(leaky02(s4 + di)), e5 = __expf(leaky02(s5 + di));
    float e6 = __expf(leaky02(s6 + di)), e7 = __expf(leaky02(s7 + di));
    den += ((e0 + e1) + (e2 + e3)) + ((e4 + e5) + (e6 + e7));
    acc += e0 * h0 + e1 * h1 + e2 * h2 + e3 * h3;
    acc += e4 * h4 + e5 * h5 + e6 * h6 + e7 * h7;
  }
  for (; k < cnt; ++k) {
    int j = csr[start + k];
    float ex = __expf(leaky02(sv[j] + di));
    den += ex;
    acc += ex * h[(size_t)j * 32 + lane];
  }
  out[(size_t)node * 32 + lane] = fmaxf(acc / den + bias[lane], 0.f);
}

// ---------------- small 32x32 GEMM (h1 @ W_g2) fused with s2/d2 ----------------
__global__ __launch_bounds__(256) void k_small_gemm_sd(
    const float* __restrict__ hin, const float* __restrict__ W,
    const float* __restrict__ as_, const float* __restrict__ ad_,
    float* __restrict__ gout, float* __restrict__ sv, float* __restrict__ dv,
    int N) {
  __shared__ float Ws[32][32];
  {
    int t = threadIdx.x;
#pragma unroll
    for (int r = 0; r < 4; ++r) {
      int idx = t + r * 256;
      Ws[idx >> 5][idx & 31] = W[idx];
    }
  }
  __syncthreads();
  int lane = threadIdx.x & 31;
  int row = blockIdx.x * 8 + (threadIdx.x >> 5);
  if (row >= N) return;
  float hv = hin[(size_t)row * 32 + lane];
  float acc = 0.f;
#pragma unroll
  for (int k = 0; k < 32; ++k) acc += __shfl(hv, k, 32) * Ws[k][lane];
  gout[(size_t)row * 32 + lane] = acc;
  float a = acc * as_[lane];
  float b = acc * ad_[lane];
#pragma unroll
  for (int w = 16; w >= 1; w >>= 1) {
    a += __shfl_xor(a, w);
    b += __shfl_xor(b, w);
  }
  if (lane == 0) {
    sv[row] = a;
    dv[row] = b;
  }
}

// ---------------- k_final2: 64 rows x 256 cols per block, fused BN3 finalize ----
__global__ __launch_bounds__(256) void k_final2(
    const float* __restrict__ mlp3, const float* __restrict__ sum3,
    const float* __restrict__ sq3, const float* __restrict__ g3,
    const float* __restrict__ be3, float invM, const float* __restrict__ h2,
    const float* __restrict__ Wgf, const float* __restrict__ bgf,
    const float* __restrict__ Wf, const float* __restrict__ bf,
    float* __restrict__ out, int N) {
  __shared__ float WfS[32 * 256];    // 32 KB
  __shared__ float Bl[64][36];       // h2 tile, then blend tile
  __shared__ float WgfS[32][33];
  __shared__ float colS[3][32];      // sc3, sh3, bgf
  const int t = threadIdx.x;
  const int row0 = blockIdx.x * 64;

  {
    const float4* src = reinterpret_cast<const float4*>(Wf);
    float4* dst = reinterpret_cast<float4*>(WfS);
#pragma unroll
    for (int r = 0; r < 8; ++r) dst[t + r * 256] = src[t + r * 256];
  }
#pragma unroll
  for (int r = 0; r < 4; ++r) {
    int idx = t + r * 256;
    WgfS[idx >> 5][idx & 31] = Wgf[idx];
  }
  if (t < 32) {
    float mean = sum3[t] * invM;
    float var = sq3[t] * invM - mean * mean;
    float rs = rsqrtf(var + 1e-5f);
    float sc = rs * g3[t];
    colS[0][t] = sc;
    colS[1][t] = be3[t] - mean * sc;
    colS[2][t] = bgf[t];
  }
#pragma unroll
  for (int r = 0; r < 2; ++r) {
    int idx = t + r * 256;   // 0..511
    int row = idx >> 3;
    int k4 = idx & 7;
    int grow = row0 + row;
    float4 v = make_float4(0.f, 0.f, 0.f, 0.f);
    if (grow < N) v = *reinterpret_cast<const float4*>(&h2[(size_t)grow * 32 + k4 * 4]);
    *reinterpret_cast<float4*>(&Bl[row][k4 * 4]) = v;
  }
  __syncthreads();

  // ---- phase 1: blend ----
  const int col = t & 31;
  const int rb = t >> 5;
  float w[32];
#pragma unroll
  for (int k = 0; k < 32; ++k) w[k] = WgfS[k][col];
  float bl[8];
#pragma unroll
  for (int r = 0; r < 8; ++r) {
    int row = rb + 8 * r;
    float a = colS[2][col];
#pragma unroll
    for (int k4 = 0; k4 < 8; ++k4) {
      float4 hv = *reinterpret_cast<const float4*>(&Bl[row][k4 * 4]);
      a += hv.x * w[k4 * 4 + 0] + hv.y * w[k4 * 4 + 1] +
           hv.z * w[k4 * 4 + 2] + hv.w * w[k4 * 4 + 3];
    }
    int grow = row0 + row;
    float pre = (grow < N) ? mlp3[(size_t)grow * 32 + col] : 0.f;
    float rv = fmaxf(pre * colS[0][col] + colS[1][col], 0.f);
    bl[r] = 0.5f * rv + 0.5f * a;
  }
  __syncthreads();
#pragma unroll
  for (int r = 0; r < 8; ++r) Bl[rb + 8 * r][col] = bl[r];
  __syncthreads();

  // ---- phase 2: out = relu(blend @ Wf + bf) ----
  const int cg = t & 31;
  const int rowg = t >> 5;
  const float4* Wf4 = reinterpret_cast<const float4*>(WfS);
  float4 acc0[8], acc1[8];
#pragma unroll
  for (int r = 0; r < 8; ++r) {
    acc0[r] = make_float4(0.f, 0.f, 0.f, 0.f);
    acc1[r] = make_float4(0.f, 0.f, 0.f, 0.f);
  }
  for (int k = 0; k < 32; k += 4) {
    float4 a[8];
#pragma unroll
    for (int r = 0; r < 8; ++r)
      a[r] = *reinterpret_cast<const float4*>(&Bl[rowg + 8 * r][k]);
    float4 b0[4], b1[4];
#pragma unroll
    for (int i = 0; i < 4; ++i) {
      b0[i] = Wf4[(k + i) * 64 + cg];
      b1[i] = Wf4[(k + i) * 64 + cg + 32];
    }
#pragma unroll
    for (int r = 0; r < 8; ++r) {
      float av[4] = {a[r].x, a[r].y, a[r].z, a[r].w};
#pragma unroll
      for (int i = 0; i < 4; ++i) {
        acc0[r].x += av[i] * b0[i].x;
        acc0[r].y += av[i] * b0[i].y;
        acc0[r].z += av[i] * b0[i].z;
        acc0[r].w += av[i] * b0[i].w;
        acc1[r].x += av[i] * b1[i].x;
        acc1[r].y += av[i] * b1[i].y;
        acc1[r].z += av[i] * b1[i].z;
        acc1[r].w += av[i] * b1[i].w;
      }
    }
  }
  float4 bfA = reinterpret_cast<const float4*>(bf)[cg];
  float4 bfB = reinterpret_cast<const float4*>(bf)[cg + 32];
  float4* out4 = reinterpret_cast<float4*>(out);
#pragma unroll
  for (int r = 0; r < 8; ++r) {
    int grow = row0 + rowg + 8 * r;
    if (grow < N) {
      float4 o0 = acc0[r], o1 = acc1[r];
      o0.x = fmaxf(o0.x + bfA.x, 0.f); o0.y = fmaxf(o0.y + bfA.y, 0.f);
      o0.z = fmaxf(o0.z + bfA.z, 0.f); o0.w = fmaxf(o0.w + bfA.w, 0.f);
      o1.x = fmaxf(o1.x + bfB.x, 0.f); o1.y = fmaxf(o1.y + bfB.y, 0.f);
      o1.z = fmaxf(o1.z + bfB.z, 0.f); o1.w = fmaxf(o1.w + bfB.w, 0.f);
      out4[(size_t)grow * 64 + cg] = o0;
      out4[(size_t)grow * 64 + cg + 32] = o1;
    }
  }
}

extern "C" void kernel_launch(void* const* d_in, const int* in_sizes, int n_in,
                              void* d_out, int out_size, void* d_ws, size_t ws_size,
                              hipStream_t stream) {
  const float* x = (const float*)d_in[0];
  const int* edge = (const int*)d_in[1];
  const float* W_g1 = (const float*)d_in[2];
  const float* as_g1 = (const float*)d_in[3];
  const float* ad_g1 = (const float*)d_in[4];
  const float* b_g1 = (const float*)d_in[5];
  const float* W_g2 = (const float*)d_in[6];
  const float* as_g2 = (const float*)d_in[7];
  const float* ad_g2 = (const float*)d_in[8];
  const float* b_g2 = (const float*)d_in[9];
  const float* W_gf = (const float*)d_in[10];
  const float* b_gf = (const float*)d_in[11];
  const float* W_m1 = (const float*)d_in[12];
  const float* b_m1 = (const float*)d_in[13];
  const float* g_m1 = (const float*)d_in[14];
  const float* be_m1 = (const float*)d_in[15];
  const float* W_m2 = (const float*)d_in[16];
  const float* b_m2 = (const float*)d_in[17];
  const float* g_m2 = (const float*)d_in[18];
  const float* be_m2 = (const float*)d_in[19];
  const float* W_m3 = (const float*)d_in[20];
  const float* b_m3 = (const float*)d_in[21];
  const float* g_m3 = (const float*)d_in[22];
  const float* be_m3 = (const float*)d_in[23];
  const float* W_f = (const float*)d_in[24];
  const float* b_f = (const float*)d_in[25];
  float* out = (float*)d_out;

  const int N = NNODES, E = NEDGES;
  const float invM = 1.f / N;
  const int* esrc = edge;
  const int* edst = edge + E;

  // ---- workspace layout ----
  float* ws = (float*)d_ws;
  float* g1 = ws;                              // N*32
  float* mlp1 = g1 + (size_t)N * 32;           // N*64
  float* mlp2 = mlp1 + (size_t)N * 64;         // N*64 (first 6.4MB doubles as binned[] early)
  float* mlp3 = mlp2 + (size_t)N * 64;         // N*32
  float* h1 = mlp3 + (size_t)N * 32;           // N*32
  float* g2 = h1 + (size_t)N * 32;             // N*32
  float* h2 = g2 + (size_t)N * 32;             // N*32
  float* s1 = h2 + (size_t)N * 32;             // N
  float* d1 = s1 + N;
  float* s2 = d1 + N;
  float* d2 = s2 + N;
  float* stats = d2 + N;                        // 384 floats (zeroed)
  float* sum1 = stats, *sq1 = stats + 64;
  float* sum2 = stats + 128, *sq2 = stats + 192;
  float* sum3 = stats + 256, *sq3 = stats + 288;
  int* ip = (int*)(stats + 384);
  int* gcnt = ip;              // 256 (zeroed)
  int* base = gcnt + 256;      // 256 (197 used)
  int* cursor = base + 256;    // 256
  int* deg = cursor + 256;     // N
  int* offs = deg + N;         // N
  int* csr = offs + N;         // E
  unsigned* binned = (unsigned*)mlp2;  // E (dead before gemm2 writes mlp2)

  hipMemsetAsync(gcnt, 0, 256 * sizeof(int), stream);
  hipMemsetAsync(stats, 0, 384 * sizeof(float), stream);

  // ---- CSR build via binned counting sort ----
  k_b0<<<(E + CNT_CH - 1) / CNT_CH, 256, 0, stream>>>(edst, gcnt, E);
  k_b1<<<1, 256, 0, stream>>>(gcnt, base, cursor);
  k_bin<<<(E + BIN_CH - 1) / BIN_CH, 256, 0, stream>>>(esrc, edst, cursor, binned, E);
  k_sort<<<NBUCK, 256, 0, stream>>>(binned, base, deg, offs, csr);

  const int GB64 = (N + 63) / 64;    // 782 blocks
  const int GB128 = (N + 127) / 128; // 391 blocks

  // ---- fused first layer: x @ [W_m1 | W_g1] -> mlp1 (+b_m1, +stats), g1 ----
  k_gemm<256, 96, 6, 64, false, true, 64><<<GB64, 256, 0, stream>>>(
      x, nullptr, nullptr, nullptr, nullptr, invM, W_m1, W_g1, b_m1,
      mlp1, g1, sum1, sq1, N);
  k_sdot<<<(N + 7) / 8, 256, 0, stream>>>(g1, as_g1, ad_g1, s1, d1, N);
  k_gat_agg<<<(N + 7) / 8, 256, 0, stream>>>(g1, s1, d1, offs, deg, csr, b_g1, h1, N);

  // ---- MLP layer 2: BN1+ReLU(mlp1) @ W_m2 + b_m2 (+stats) ----
  k_gemm<64, 64, 4, 64, true, true, 128><<<GB128, 256, 0, stream>>>(
      mlp1, sum1, sq1, g_m1, be_m1, invM, W_m2, nullptr, b_m2,
      mlp2, nullptr, sum2, sq2, N);

  // ---- GAT layer 2 ----
  k_small_gemm_sd<<<(N + 7) / 8, 256, 0, stream>>>(h1, W_g2, as_g2, ad_g2, g2, s2, d2, N);
  k_gat_agg<<<(N + 7) / 8, 256, 0, stream>>>(g2, s2, d2, offs, deg, csr, b_g2, h2, N);

  // ---- MLP layer 3: BN2+ReLU(mlp2) @ W_m3 + b_m3 (+stats) ----
  k_gemm<64, 32, 2, 32, true, true, 128><<<GB128, 256, 0, stream>>>(
      mlp2, sum2, sq2, g_m2, be_m2, invM, W_m3, nullptr, b_m3,
      mlp3, nullptr, sum3, sq3, N);

  // ---- final fused: BN3 + blend + @W_f + b_f + ReLU ----
  k_final2<<<(N + 63) / 64, 256, 0, stream>>>(mlp3, sum3, sq3, g_m3, be_m3, invM,
                                              h2, W_gf, b_gf, W_f, b_f, out, N);
}